// Round 1
// baseline (2578.842 us; speedup 1.0000x reference)
//
#include <hip/hip_runtime.h>
#include <hip/hip_bf16.h>

// Problem constants (match reference)
#define NODES 100000
#define EDGES 1600000
#define FEAT  128
#define HID   256
#define CLS   64
#define KPROP 10
#define ALPHA_C 0.1f
#define BETA_C  0.5f
#define BN_EPS  1e-5f

// ---------------------------------------------------------------------------
// GEMM: out[M,N] = act(A)[M,K] @ W[K,N] + bias, optional fused per-K-column
// BN affine + ReLU applied to A on load (BN of the PREVIOUS layer).
// BM=64, BN=64, BK=32, 256 threads, 4x4 micro-tile per thread.
// ---------------------------------------------------------------------------
template<bool FUSE_BN_RELU>
__global__ __launch_bounds__(256)
void gemm_k(const float* __restrict__ A, const float* __restrict__ W,
            const float* __restrict__ bias,
            const float* __restrict__ scale, const float* __restrict__ shift,
            float* __restrict__ out, int M, int K, int N)
{
    const int BM = 64, BN = 64, BK = 32;
    __shared__ float As[BK][BM + 1];   // k-major so per-k row reads are contiguous
    __shared__ float Ws[BK][BN];

    const int m0 = blockIdx.x * BM;
    const int n0 = blockIdx.y * BN;
    const int tid = threadIdx.x;
    const int tc = tid & 15;           // 16 col-groups of 4
    const int tr = tid >> 4;           // 16 row-groups of 4

    float acc[4][4] = {};

    for (int k0 = 0; k0 < K; k0 += BK) {
        // Load A tile (64 rows x 32 k), transposed into As[k][m]
        #pragma unroll
        for (int i = 0; i < 8; ++i) {
            int mm = (tid >> 5) + 8 * i;     // 0..63
            int kk = tid & 31;               // 0..31
            int gr = m0 + mm;
            float v = (gr < M) ? A[(size_t)gr * K + (k0 + kk)] : 0.f;
            if constexpr (FUSE_BN_RELU) {
                v = fmaxf(v * scale[k0 + kk] + shift[k0 + kk], 0.f);
            }
            As[kk][mm] = v;
        }
        // Load W tile (32 k x 64 n), row-major
        #pragma unroll
        for (int i = 0; i < 8; ++i) {
            int kk = (tid >> 6) + 4 * i;     // 0..31
            int nn = tid & 63;               // 0..63
            Ws[kk][nn] = W[(size_t)(k0 + kk) * N + (n0 + nn)];
        }
        __syncthreads();

        #pragma unroll
        for (int kk = 0; kk < BK; ++kk) {
            float a[4], b[4];
            #pragma unroll
            for (int i = 0; i < 4; ++i) a[i] = As[kk][tr * 4 + i];
            #pragma unroll
            for (int j = 0; j < 4; ++j) b[j] = Ws[kk][tc * 4 + j];
            #pragma unroll
            for (int i = 0; i < 4; ++i)
                #pragma unroll
                for (int j = 0; j < 4; ++j)
                    acc[i][j] = fmaf(a[i], b[j], acc[i][j]);
        }
        __syncthreads();
    }

    #pragma unroll
    for (int i = 0; i < 4; ++i) {
        int gr = m0 + tr * 4 + i;
        if (gr < M) {
            #pragma unroll
            for (int j = 0; j < 4; ++j) {
                int gc = n0 + tc * 4 + j;
                out[(size_t)gr * N + gc] = acc[i][j] + bias[gc];
            }
        }
    }
}

// ---------------------------------------------------------------------------
// BN batch statistics: per-column sum and sum-of-squares over all rows.
// 256 threads = 256 columns (coalesced), 512 rows per block, atomic partials.
// ---------------------------------------------------------------------------
__global__ __launch_bounds__(256)
void stats_k(const float* __restrict__ h, float* __restrict__ sum,
             float* __restrict__ sq)
{
    int col = threadIdx.x;
    int r0 = blockIdx.x * 512;
    int rend = min(r0 + 512, NODES);
    float s = 0.f, q = 0.f;
    for (int r = r0; r < rend; ++r) {
        float v = h[(size_t)r * HID + col];
        s += v;
        q += v * v;
    }
    atomicAdd(&sum[col], s);
    atomicAdd(&sq[col], q);
}

__global__ void bnfin_k(const float* __restrict__ sum, const float* __restrict__ sq,
                        const float* __restrict__ g, const float* __restrict__ be,
                        float* __restrict__ scale, float* __restrict__ shift)
{
    int c = threadIdx.x;  // 256
    float mu = sum[c] * (1.f / NODES);
    float var = sq[c] * (1.f / NODES) - mu * mu;
    float sc = g[c] * rsqrtf(var + BN_EPS);
    scale[c] = sc;
    shift[c] = be[c] - mu * sc;
}

// ---------------------------------------------------------------------------
// use_x flag: any nonzero in z_sam -> flag=1 (flag pre-zeroed)
// ---------------------------------------------------------------------------
__global__ void flag_k(const float* __restrict__ zs, int* __restrict__ flag)
{
    int i = blockIdx.x * 256 + threadIdx.x;
    bool nz = (i < NODES * CLS) && (zs[i] != 0.f);
    if (__any(nz)) {
        if ((threadIdx.x & 63) == 0) *flag = 1;
    }
}

__global__ void blend_k(const float* __restrict__ zs, const float* __restrict__ logits,
                        const int* __restrict__ flag, float* __restrict__ z0)
{
    int i = blockIdx.x * 256 + threadIdx.x;
    if (i < NODES * CLS) {
        float l = logits[i];
        z0[i] = (*flag) ? ((1.f - BETA_C) * zs[i] + BETA_C * l) : l;
    }
}

// ---------------------------------------------------------------------------
// CSR build: histogram -> 2-level exclusive scan -> fill
// ---------------------------------------------------------------------------
__global__ void count_k(const int* __restrict__ dst, int* __restrict__ cnt)
{
    int i = blockIdx.x * 256 + threadIdx.x;
    if (i < EDGES) atomicAdd(&cnt[dst[i]], 1);
}

__global__ void scan1_k(const int* __restrict__ cnt, int* __restrict__ rowptr,
                        int* __restrict__ bsum)
{
    __shared__ int s[256];
    int tid = threadIdx.x;
    int i = blockIdx.x * 256 + tid;
    int v = (i < NODES) ? cnt[i] : 0;
    s[tid] = v;
    __syncthreads();
    for (int off = 1; off < 256; off <<= 1) {
        int t = (tid >= off) ? s[tid - off] : 0;
        __syncthreads();
        s[tid] += t;
        __syncthreads();
    }
    if (i < NODES) rowptr[i] = s[tid] - v;          // exclusive within block
    if (tid == 255) bsum[blockIdx.x] = s[255];
}

__global__ void scan2_k(const int* __restrict__ bsum, int* __restrict__ boffs, int nb)
{
    __shared__ int s[512];
    int tid = threadIdx.x;
    int v = (tid < nb) ? bsum[tid] : 0;
    s[tid] = v;
    __syncthreads();
    for (int off = 1; off < 512; off <<= 1) {
        int t = (tid >= off) ? s[tid - off] : 0;
        __syncthreads();
        s[tid] += t;
        __syncthreads();
    }
    if (tid < nb) boffs[tid] = s[tid] - v;
}

__global__ void scan3_k(int* __restrict__ rowptr, const int* __restrict__ boffs,
                        int* __restrict__ cursor)
{
    int i = blockIdx.x * 256 + threadIdx.x;
    if (i < NODES) {
        int v = rowptr[i] + boffs[blockIdx.x];
        rowptr[i] = v;
        cursor[i] = v;
    }
    if (i == 0) rowptr[NODES] = EDGES;
}

__global__ void fill_k(const int* __restrict__ src, const int* __restrict__ dst,
                       const float* __restrict__ w, int* __restrict__ cursor,
                       int* __restrict__ esrc, float* __restrict__ ew)
{
    int i = blockIdx.x * 256 + threadIdx.x;
    if (i < EDGES) {
        int d = dst[i];
        int pos = atomicAdd(&cursor[d], 1);
        esrc[pos] = src[i];
        ew[pos] = w[i];
    }
}

// ---------------------------------------------------------------------------
// Propagation step: one wave per row, lane = class column.
// zout[r,c] = (1-alpha) * sum_e w[e]*zin[esrc[e],c] + alpha*logits[r,c]
// ---------------------------------------------------------------------------
__global__ __launch_bounds__(256)
void prop_k(const int* __restrict__ rowptr, const int* __restrict__ esrc,
            const float* __restrict__ ew, const float* __restrict__ zin,
            const float* __restrict__ logits, float* __restrict__ zout)
{
    int row = blockIdx.x * 4 + (threadIdx.x >> 6);
    if (row >= NODES) return;
    int lane = threadIdx.x & 63;
    int beg = rowptr[row], end = rowptr[row + 1];
    float acc = 0.f;
    for (int e = beg; e < end; ++e) {
        acc = fmaf(ew[e], zin[(size_t)esrc[e] * CLS + lane], acc);
    }
    int o = row * CLS + lane;
    zout[o] = (1.f - ALPHA_C) * acc + ALPHA_C * logits[o];
}

// ---------------------------------------------------------------------------
// log_softmax over C=64 (exactly one wave wide)
// ---------------------------------------------------------------------------
__global__ __launch_bounds__(256)
void logsoftmax_k(const float* __restrict__ z, float* __restrict__ out)
{
    int row = blockIdx.x * 4 + (threadIdx.x >> 6);
    if (row >= NODES) return;
    int lane = threadIdx.x & 63;
    float v = z[row * CLS + lane];
    float m = v;
    #pragma unroll
    for (int off = 32; off > 0; off >>= 1) m = fmaxf(m, __shfl_xor(m, off, 64));
    float ex = expf(v - m);
    float s = ex;
    #pragma unroll
    for (int off = 32; off > 0; off >>= 1) s += __shfl_xor(s, off, 64);
    out[row * CLS + lane] = (v - m) - logf(s);
}

// ---------------------------------------------------------------------------
extern "C" void kernel_launch(void* const* d_in, const int* in_sizes, int n_in,
                              void* d_out, int out_size, void* d_ws, size_t ws_size,
                              hipStream_t stream)
{
    const float* x   = (const float*)d_in[0];
    const int*   src = (const int*)d_in[1];
    const int*   dst = (const int*)d_in[2];
    const float* w   = (const float*)d_in[3];
    const float* W1  = (const float*)d_in[4];
    const float* b1  = (const float*)d_in[5];
    const float* g1  = (const float*)d_in[6];
    const float* be1 = (const float*)d_in[7];
    const float* W2  = (const float*)d_in[8];
    const float* b2  = (const float*)d_in[9];
    const float* g2  = (const float*)d_in[10];
    const float* be2 = (const float*)d_in[11];
    const float* W3  = (const float*)d_in[12];
    const float* b3  = (const float*)d_in[13];
    const float* zsam = (const float*)d_in[14];
    float* outp = (float*)d_out;

    // Workspace layout (needs ~205 MB):
    //   header 4096 floats: scale1/shift1/scale2/shift2/sum/sq/flag
    //   bufA: 25.6M floats  (h1_raw; later logits, zA, zB)
    //   bufB: 25.6M floats  (h2_raw; later CSR arrays)
    float* wsf = (float*)d_ws;
    float* s_scale1 = wsf;
    float* s_shift1 = wsf + 256;
    float* s_scale2 = wsf + 512;
    float* s_shift2 = wsf + 768;
    float* s_sum    = wsf + 1024;
    float* s_sq     = wsf + 1280;
    int*   flag     = (int*)(wsf + 1536);

    float* bufA = wsf + 4096;
    float* bufB = bufA + (size_t)NODES * HID;      // 25.6M floats each

    float* h1_raw = bufA;
    float* h2_raw = bufB;
    float* logits = bufA;                           // reuse after h1 dead
    float* zA     = bufA + (size_t)NODES * CLS;     // +6.4M
    float* zB     = bufA + (size_t)2 * NODES * CLS; // +12.8M

    // CSR arrays overlay bufB (only used after GEMM3 is done reading h2_raw)
    int*   esrc    = (int*)bufB;
    float* ew      = bufB + EDGES;
    int*   rowptr  = (int*)(bufB + 2 * (size_t)EDGES);
    int*   cursor  = rowptr + (NODES + 1);
    int*   bsum    = cursor + NODES;
    int*   boffs   = bsum + 512;
    int*   cnt     = boffs + 512;

    const int MTILES = (NODES + 63) / 64;           // 1563
    const int SCANB  = (NODES + 255) / 256;         // 391

    // ---- Layer 1: h1_raw = x @ W1 + b1 ; BN stats ----
    hipMemsetAsync(s_sum, 0, 512 * sizeof(float), stream);
    gemm_k<false><<<dim3(MTILES, HID / 64), 256, 0, stream>>>(
        x, W1, b1, nullptr, nullptr, h1_raw, NODES, FEAT, HID);
    stats_k<<<(NODES + 511) / 512, 256, 0, stream>>>(h1_raw, s_sum, s_sq);
    bnfin_k<<<1, 256, 0, stream>>>(s_sum, s_sq, g1, be1, s_scale1, s_shift1);

    // ---- Layer 2: h2_raw = relu(bn(h1_raw)) @ W2 + b2 ; BN stats ----
    hipMemsetAsync(s_sum, 0, 512 * sizeof(float), stream);
    gemm_k<true><<<dim3(MTILES, HID / 64), 256, 0, stream>>>(
        h1_raw, W2, b2, s_scale1, s_shift1, h2_raw, NODES, HID, HID);
    stats_k<<<(NODES + 511) / 512, 256, 0, stream>>>(h2_raw, s_sum, s_sq);
    bnfin_k<<<1, 256, 0, stream>>>(s_sum, s_sq, g2, be2, s_scale2, s_shift2);

    // ---- Layer 3: logits = relu(bn(h2_raw)) @ W3 + b3  (into bufA) ----
    gemm_k<true><<<dim3(MTILES, CLS / 64), 256, 0, stream>>>(
        h2_raw, W3, b3, s_scale2, s_shift2, logits, NODES, HID, CLS);

    // ---- Warm-start blend: z0 = flag ? (1-beta)*z_sam + beta*logits : logits
    hipMemsetAsync(flag, 0, sizeof(int), stream);
    flag_k<<<(NODES * CLS + 255) / 256, 256, 0, stream>>>(zsam, flag);
    blend_k<<<(NODES * CLS + 255) / 256, 256, 0, stream>>>(zsam, logits, flag, zA);

    // ---- CSR build (by dst) in bufB ----
    hipMemsetAsync(cnt, 0, NODES * sizeof(int), stream);
    count_k<<<(EDGES + 255) / 256, 256, 0, stream>>>(dst, cnt);
    scan1_k<<<SCANB, 256, 0, stream>>>(cnt, rowptr, bsum);
    scan2_k<<<1, 512, 0, stream>>>(bsum, boffs, SCANB);
    scan3_k<<<SCANB, 256, 0, stream>>>(rowptr, boffs, cursor);
    fill_k<<<(EDGES + 255) / 256, 256, 0, stream>>>(src, dst, w, cursor, esrc, ew);

    // ---- K=10 propagation steps, ping-pong zA <-> zB ----
    for (int it = 0; it < KPROP; ++it) {
        const float* zi = (it & 1) ? zB : zA;
        float* zo = (it & 1) ? zA : zB;
        prop_k<<<(NODES + 3) / 4, 256, 0, stream>>>(rowptr, esrc, ew, zi, logits, zo);
    }
    // KPROP even -> final result in zA

    // ---- log_softmax -> d_out ----
    logsoftmax_k<<<(NODES + 3) / 4, 256, 0, stream>>>(zA, outp);
}

// Round 2
// 1550.192 us; speedup vs baseline: 1.6636x; 1.6636x over previous
//
#include <hip/hip_runtime.h>
#include <hip/hip_bf16.h>

// Problem constants (match reference)
#define NODES 100000
#define EDGES 1600000
#define FEAT  128
#define HID   256
#define CLS   64
#define KPROP 10
#define ALPHA_C 0.1f
#define BETA_C  0.5f
#define BN_EPS  1e-5f

// ---------------------------------------------------------------------------
// GEMM: out[M,N] = act(A)[M,K] @ W[K,N] + bias, optional fused per-K-column
// BN affine + ReLU applied to A on load (BN of the PREVIOUS layer).
// BM=64, BN=64, BK=32, 256 threads, 4x4 micro-tile per thread.
// ---------------------------------------------------------------------------
template<bool FUSE_BN_RELU>
__global__ __launch_bounds__(256)
void gemm_k(const float* __restrict__ A, const float* __restrict__ W,
            const float* __restrict__ bias,
            const float* __restrict__ scale, const float* __restrict__ shift,
            float* __restrict__ out, int M, int K, int N)
{
    const int BM = 64, BN = 64, BK = 32;
    __shared__ float As[BK][BM + 1];   // k-major so per-k row reads are contiguous
    __shared__ float Ws[BK][BN];

    const int m0 = blockIdx.x * BM;
    const int n0 = blockIdx.y * BN;
    const int tid = threadIdx.x;
    const int tc = tid & 15;           // 16 col-groups of 4
    const int tr = tid >> 4;           // 16 row-groups of 4

    float acc[4][4] = {};

    for (int k0 = 0; k0 < K; k0 += BK) {
        // Load A tile (64 rows x 32 k), transposed into As[k][m]
        #pragma unroll
        for (int i = 0; i < 8; ++i) {
            int mm = (tid >> 5) + 8 * i;     // 0..63
            int kk = tid & 31;               // 0..31
            int gr = m0 + mm;
            float v = (gr < M) ? A[(size_t)gr * K + (k0 + kk)] : 0.f;
            if constexpr (FUSE_BN_RELU) {
                v = fmaxf(v * scale[k0 + kk] + shift[k0 + kk], 0.f);
            }
            As[kk][mm] = v;
        }
        // Load W tile (32 k x 64 n), row-major
        #pragma unroll
        for (int i = 0; i < 8; ++i) {
            int kk = (tid >> 6) + 4 * i;     // 0..31
            int nn = tid & 63;               // 0..63
            Ws[kk][nn] = W[(size_t)(k0 + kk) * N + (n0 + nn)];
        }
        __syncthreads();

        #pragma unroll
        for (int kk = 0; kk < BK; ++kk) {
            float a[4], b[4];
            #pragma unroll
            for (int i = 0; i < 4; ++i) a[i] = As[kk][tr * 4 + i];
            #pragma unroll
            for (int j = 0; j < 4; ++j) b[j] = Ws[kk][tc * 4 + j];
            #pragma unroll
            for (int i = 0; i < 4; ++i)
                #pragma unroll
                for (int j = 0; j < 4; ++j)
                    acc[i][j] = fmaf(a[i], b[j], acc[i][j]);
        }
        __syncthreads();
    }

    #pragma unroll
    for (int i = 0; i < 4; ++i) {
        int gr = m0 + tr * 4 + i;
        if (gr < M) {
            #pragma unroll
            for (int j = 0; j < 4; ++j) {
                int gc = n0 + tc * 4 + j;
                out[(size_t)gr * N + gc] = acc[i][j] + bias[gc];
            }
        }
    }
}

// ---------------------------------------------------------------------------
// BN batch statistics: per-column sum and sum-of-squares over all rows.
// ---------------------------------------------------------------------------
__global__ __launch_bounds__(256)
void stats_k(const float* __restrict__ h, float* __restrict__ sum,
             float* __restrict__ sq)
{
    int col = threadIdx.x;
    int r0 = blockIdx.x * 512;
    int rend = min(r0 + 512, NODES);
    float s = 0.f, q = 0.f;
    for (int r = r0; r < rend; ++r) {
        float v = h[(size_t)r * HID + col];
        s += v;
        q += v * v;
    }
    atomicAdd(&sum[col], s);
    atomicAdd(&sq[col], q);
}

__global__ void bnfin_k(const float* __restrict__ sum, const float* __restrict__ sq,
                        const float* __restrict__ g, const float* __restrict__ be,
                        float* __restrict__ scale, float* __restrict__ shift)
{
    int c = threadIdx.x;  // 256
    float mu = sum[c] * (1.f / NODES);
    float var = sq[c] * (1.f / NODES) - mu * mu;
    float sc = g[c] * rsqrtf(var + BN_EPS);
    scale[c] = sc;
    shift[c] = be[c] - mu * sc;
}

// ---------------------------------------------------------------------------
// use_x flag: any nonzero in z_sam -> flag=1 (flag pre-zeroed)
// ---------------------------------------------------------------------------
__global__ void flag_k(const float* __restrict__ zs, int* __restrict__ flag)
{
    int i = blockIdx.x * 256 + threadIdx.x;
    bool nz = (i < NODES * CLS) && (zs[i] != 0.f);
    if (__any(nz)) {
        if ((threadIdx.x & 63) == 0) *flag = 1;
    }
}

// z0 (bf16) = flag ? (1-beta)*z_sam + beta*logits : logits
__global__ void blend_k(const float* __restrict__ zs, const float* __restrict__ logits,
                        const int* __restrict__ flag, __hip_bfloat16* __restrict__ z0)
{
    int i = blockIdx.x * 256 + threadIdx.x;
    if (i < NODES * CLS) {
        float l = logits[i];
        float v = (*flag) ? ((1.f - BETA_C) * zs[i] + BETA_C * l) : l;
        z0[i] = __float2bfloat16(v);
    }
}

// ---------------------------------------------------------------------------
// CSR build: histogram -> 2-level exclusive scan -> fill
// ---------------------------------------------------------------------------
__global__ void count_k(const int* __restrict__ dst, int* __restrict__ cnt)
{
    int i = blockIdx.x * 256 + threadIdx.x;
    if (i < EDGES) atomicAdd(&cnt[dst[i]], 1);
}

__global__ void scan1_k(const int* __restrict__ cnt, int* __restrict__ rowptr,
                        int* __restrict__ bsum)
{
    __shared__ int s[256];
    int tid = threadIdx.x;
    int i = blockIdx.x * 256 + tid;
    int v = (i < NODES) ? cnt[i] : 0;
    s[tid] = v;
    __syncthreads();
    for (int off = 1; off < 256; off <<= 1) {
        int t = (tid >= off) ? s[tid - off] : 0;
        __syncthreads();
        s[tid] += t;
        __syncthreads();
    }
    if (i < NODES) rowptr[i] = s[tid] - v;          // exclusive within block
    if (tid == 255) bsum[blockIdx.x] = s[255];
}

__global__ void scan2_k(const int* __restrict__ bsum, int* __restrict__ boffs, int nb)
{
    __shared__ int s[512];
    int tid = threadIdx.x;
    int v = (tid < nb) ? bsum[tid] : 0;
    s[tid] = v;
    __syncthreads();
    for (int off = 1; off < 512; off <<= 1) {
        int t = (tid >= off) ? s[tid - off] : 0;
        __syncthreads();
        s[tid] += t;
        __syncthreads();
    }
    if (tid < nb) boffs[tid] = s[tid] - v;
}

__global__ void scan3_k(int* __restrict__ rowptr, const int* __restrict__ boffs,
                        int* __restrict__ cursor)
{
    int i = blockIdx.x * 256 + threadIdx.x;
    if (i < NODES) {
        int v = rowptr[i] + boffs[blockIdx.x];
        rowptr[i] = v;
        cursor[i] = v;
    }
    if (i == 0) rowptr[NODES] = EDGES;
}

__global__ void fill_k(const int* __restrict__ src, const int* __restrict__ dst,
                       const float* __restrict__ w, int* __restrict__ cursor,
                       int* __restrict__ esrc, float* __restrict__ ew)
{
    int i = blockIdx.x * 256 + threadIdx.x;
    if (i < EDGES) {
        int d = dst[i];
        int pos = atomicAdd(&cursor[d], 1);
        esrc[pos] = src[i];
        ew[pos] = w[i];
    }
}

// ---------------------------------------------------------------------------
// Propagation step: one wave per row, lane = class column. z stored as bf16
// (128B/row gather). Edge metadata loaded cooperatively (coalesced) and
// broadcast via shuffles; gather loop unrolled x4 for 4 loads in flight.
// ---------------------------------------------------------------------------
__global__ __launch_bounds__(256)
void prop_k(const int* __restrict__ rowptr, const int* __restrict__ esrc,
            const float* __restrict__ ew, const __hip_bfloat16* __restrict__ zin,
            const float* __restrict__ logits, __hip_bfloat16* __restrict__ zout)
{
    int row = blockIdx.x * 4 + (threadIdx.x >> 6);
    if (row >= NODES) return;
    int lane = threadIdx.x & 63;
    int beg = rowptr[row], end = rowptr[row + 1];
    float acc = 0.f;

    for (int cbeg = beg; cbeg < end; cbeg += 64) {
        // cooperative coalesced load of up to 64 edges' metadata
        int e = cbeg + lane;
        int   s_l = 0;
        float w_l = 0.f;
        if (e < end) { s_l = esrc[e]; w_l = ew[e]; }
        int cnt = min(64, end - cbeg);

        int j = 0;
        for (; j + 4 <= cnt; j += 4) {
            int   s0 = __shfl(s_l, j, 64),     s1 = __shfl(s_l, j + 1, 64);
            int   s2 = __shfl(s_l, j + 2, 64), s3 = __shfl(s_l, j + 3, 64);
            float w0 = __shfl(w_l, j, 64),     w1 = __shfl(w_l, j + 1, 64);
            float w2 = __shfl(w_l, j + 2, 64), w3 = __shfl(w_l, j + 3, 64);
            float v0 = __bfloat162float(zin[s0 * CLS + lane]);
            float v1 = __bfloat162float(zin[s1 * CLS + lane]);
            float v2 = __bfloat162float(zin[s2 * CLS + lane]);
            float v3 = __bfloat162float(zin[s3 * CLS + lane]);
            acc = fmaf(w0, v0, acc);
            acc = fmaf(w1, v1, acc);
            acc = fmaf(w2, v2, acc);
            acc = fmaf(w3, v3, acc);
        }
        for (; j < cnt; ++j) {
            int   s0 = __shfl(s_l, j, 64);
            float w0 = __shfl(w_l, j, 64);
            acc = fmaf(w0, __bfloat162float(zin[s0 * CLS + lane]), acc);
        }
    }
    int o = row * CLS + lane;
    zout[o] = __float2bfloat16((1.f - ALPHA_C) * acc + ALPHA_C * logits[o]);
}

// ---------------------------------------------------------------------------
// log_softmax over C=64 (exactly one wave wide), bf16 input, fp32 out
// ---------------------------------------------------------------------------
__global__ __launch_bounds__(256)
void logsoftmax_k(const __hip_bfloat16* __restrict__ z, float* __restrict__ out)
{
    int row = blockIdx.x * 4 + (threadIdx.x >> 6);
    if (row >= NODES) return;
    int lane = threadIdx.x & 63;
    float v = __bfloat162float(z[row * CLS + lane]);
    float m = v;
    #pragma unroll
    for (int off = 32; off > 0; off >>= 1) m = fmaxf(m, __shfl_xor(m, off, 64));
    float ex = expf(v - m);
    float s = ex;
    #pragma unroll
    for (int off = 32; off > 0; off >>= 1) s += __shfl_xor(s, off, 64);
    out[row * CLS + lane] = (v - m) - logf(s);
}

// ---------------------------------------------------------------------------
extern "C" void kernel_launch(void* const* d_in, const int* in_sizes, int n_in,
                              void* d_out, int out_size, void* d_ws, size_t ws_size,
                              hipStream_t stream)
{
    const float* x   = (const float*)d_in[0];
    const int*   src = (const int*)d_in[1];
    const int*   dst = (const int*)d_in[2];
    const float* w   = (const float*)d_in[3];
    const float* W1  = (const float*)d_in[4];
    const float* b1  = (const float*)d_in[5];
    const float* g1  = (const float*)d_in[6];
    const float* be1 = (const float*)d_in[7];
    const float* W2  = (const float*)d_in[8];
    const float* b2  = (const float*)d_in[9];
    const float* g2  = (const float*)d_in[10];
    const float* be2 = (const float*)d_in[11];
    const float* W3  = (const float*)d_in[12];
    const float* b3  = (const float*)d_in[13];
    const float* zsam = (const float*)d_in[14];
    float* outp = (float*)d_out;

    // Workspace layout:
    //   header 4096 floats: scale1/shift1/scale2/shift2/sum/sq/flag
    //   bufA: 25.6M floats  (h1_raw; later logits + bf16 zA/zB)
    //   bufB: 25.6M floats  (h2_raw; later CSR arrays)
    float* wsf = (float*)d_ws;
    float* s_scale1 = wsf;
    float* s_shift1 = wsf + 256;
    float* s_scale2 = wsf + 512;
    float* s_shift2 = wsf + 768;
    float* s_sum    = wsf + 1024;
    float* s_sq     = wsf + 1280;
    int*   flag     = (int*)(wsf + 1536);

    float* bufA = wsf + 4096;
    float* bufB = bufA + (size_t)NODES * HID;      // 25.6M floats each

    float* h1_raw = bufA;
    float* h2_raw = bufB;
    float* logits = bufA;                           // reuse after h1 dead
    __hip_bfloat16* zA = (__hip_bfloat16*)(bufA + (size_t)NODES * CLS);       // bf16, 12.8MB
    __hip_bfloat16* zB = (__hip_bfloat16*)(bufA + (size_t)NODES * CLS + (size_t)NODES * CLS / 2);

    // CSR arrays overlay bufB (only used after GEMM3 is done reading h2_raw)
    int*   esrc    = (int*)bufB;
    float* ew      = bufB + EDGES;
    int*   rowptr  = (int*)(bufB + 2 * (size_t)EDGES);
    int*   cursor  = rowptr + (NODES + 1);
    int*   bsum    = cursor + NODES;
    int*   boffs   = bsum + 512;
    int*   cnt     = boffs + 512;

    const int MTILES = (NODES + 63) / 64;           // 1563
    const int SCANB  = (NODES + 255) / 256;         // 391

    // ---- Layer 1: h1_raw = x @ W1 + b1 ; BN stats ----
    hipMemsetAsync(s_sum, 0, 512 * sizeof(float), stream);
    gemm_k<false><<<dim3(MTILES, HID / 64), 256, 0, stream>>>(
        x, W1, b1, nullptr, nullptr, h1_raw, NODES, FEAT, HID);
    stats_k<<<(NODES + 511) / 512, 256, 0, stream>>>(h1_raw, s_sum, s_sq);
    bnfin_k<<<1, 256, 0, stream>>>(s_sum, s_sq, g1, be1, s_scale1, s_shift1);

    // ---- Layer 2: h2_raw = relu(bn(h1_raw)) @ W2 + b2 ; BN stats ----
    hipMemsetAsync(s_sum, 0, 512 * sizeof(float), stream);
    gemm_k<true><<<dim3(MTILES, HID / 64), 256, 0, stream>>>(
        h1_raw, W2, b2, s_scale1, s_shift1, h2_raw, NODES, HID, HID);
    stats_k<<<(NODES + 511) / 512, 256, 0, stream>>>(h2_raw, s_sum, s_sq);
    bnfin_k<<<1, 256, 0, stream>>>(s_sum, s_sq, g2, be2, s_scale2, s_shift2);

    // ---- Layer 3: logits = relu(bn(h2_raw)) @ W3 + b3  (into bufA) ----
    gemm_k<true><<<dim3(MTILES, CLS / 64), 256, 0, stream>>>(
        h2_raw, W3, b3, s_scale2, s_shift2, logits, NODES, HID, CLS);

    // ---- Warm-start blend: z0 = flag ? (1-beta)*z_sam + beta*logits : logits
    hipMemsetAsync(flag, 0, sizeof(int), stream);
    flag_k<<<(NODES * CLS + 255) / 256, 256, 0, stream>>>(zsam, flag);
    blend_k<<<(NODES * CLS + 255) / 256, 256, 0, stream>>>(zsam, logits, flag, zA);

    // ---- CSR build (by dst) in bufB ----
    hipMemsetAsync(cnt, 0, NODES * sizeof(int), stream);
    count_k<<<(EDGES + 255) / 256, 256, 0, stream>>>(dst, cnt);
    scan1_k<<<SCANB, 256, 0, stream>>>(cnt, rowptr, bsum);
    scan2_k<<<1, 512, 0, stream>>>(bsum, boffs, SCANB);
    scan3_k<<<SCANB, 256, 0, stream>>>(rowptr, boffs, cursor);
    fill_k<<<(EDGES + 255) / 256, 256, 0, stream>>>(src, dst, w, cursor, esrc, ew);

    // ---- K=10 propagation steps, ping-pong zA <-> zB ----
    for (int it = 0; it < KPROP; ++it) {
        const __hip_bfloat16* zi = (it & 1) ? zB : zA;
        __hip_bfloat16* zo = (it & 1) ? zA : zB;
        prop_k<<<(NODES + 3) / 4, 256, 0, stream>>>(rowptr, esrc, ew, zi, logits, zo);
    }
    // KPROP even -> final result in zA

    // ---- log_softmax -> d_out ----
    logsoftmax_k<<<(NODES + 3) / 4, 256, 0, stream>>>(zA, outp);
}